// Round 1
// baseline (211.730 us; speedup 1.0000x reference)
//
#include <hip/hip_runtime.h>
#include <stdint.h>

#define T_STEPS 2048
#define NSTATE  64
#define LARGEF  1.0e9f

// One block = one wave = one batch element. lane = target state.
__global__ __launch_bounds__(64) void viterbi_kernel(const float* __restrict__ in,
                                                     float* __restrict__ out) {
    __shared__ float y_lds[2 * T_STEPS];                 // 16 KB: staged input row
    __shared__ unsigned long long tb[T_STEPS];           // 16 KB: traceback words

    const int b    = blockIdx.x;
    const int lane = threadIdx.x;                        // target state t*
    const float* yrow = in + (size_t)b * (2 * T_STEPS);

    // ---- stage input row into LDS (coalesced float4) ----
    const float4* y4 = (const float4*)yrow;
    float4* l4 = (float4*)y_lds;
#pragma unroll
    for (int i = 0; i < (2 * T_STEPS) / 4 / 64; ++i) {
        l4[i * 64 + lane] = y4[i * 64 + lane];
    }
    __syncthreads();

    // ---- per-lane trellis constants ----
    // pred states of t are p0=2*(t&31) (j=0) and p0+1 (j=1); input bit u = t>>5.
    // For p0 (even state, s0=0):
    //   out0 = u ^ s4 ^ s3 ^ s1   (poly 1011011)
    //   out1 = u ^ s5 ^ s4 ^ s3   (poly 1111001)
    // where s1..s5 are bits 0..4 of (t&31). Flipping pred LSB flips BOTH outs,
    // so cand1 uses -bmv.
    const int t  = lane;
    const int p0 = 2 * (t & 31);
    const int u  = (t >> 5) & 1;
    const int s1 = t & 1, s3 = (t >> 2) & 1, s4 = (t >> 3) & 1, s5 = (t >> 4) & 1;
    const int out0 = u ^ s4 ^ s3 ^ s1;
    const int out1 = u ^ s5 ^ s4 ^ s3;
    const float sa = 1.0f - 2.0f * (float)out0;
    const float sb = 1.0f - 2.0f * (float)out1;

    float cum = (lane == 0) ? 0.0f : LARGEF;

    // ---- forward ACS ----
#pragma unroll 4
    for (int ts = 0; ts < T_STEPS; ++ts) {
        const float y0 = y_lds[2 * ts];
        const float y1 = y_lds[2 * ts + 1];
        const float bmv = fmaf(sa, y0, sb * y1);         // == sa*y0 + sb*y1, bit-exact vs ref
        const float c0 = __shfl(cum, p0);
        const float c1 = __shfl(cum, p0 + 1);
        const float cand0 = c0 + bmv;
        const float cand1 = c1 - bmv;
        const int j = (cand1 < cand0) ? 1 : 0;           // tie -> j=0 (argmin-first)
        cum = fminf(cand0, cand1);
        const unsigned long long W = __ballot(j);
        if (lane == 0) tb[ts] = W;
    }
    __syncthreads();

    // ---- terminal state: argmin over states, first index on ties ----
    float v = cum;
    int vi = lane;
#pragma unroll
    for (int off = 32; off >= 1; off >>= 1) {
        const float ov = __shfl_xor(v, off);
        const int   oi = __shfl_xor(vi, off);
        if (ov < v || (ov == v && oi < vi)) { v = ov; vi = oi; }
    }
    const int term = vi;                                  // uniform across wave

    // ---- traceback ----
    // bits[idx] = state@(idx+1) >> 5.  state@(idx) = 2*(s&31) + j, j = bit s of tb[idx].
    int s = term;                                         // state @ T
    unsigned long long acc = 0;
#pragma unroll 16
    for (int idx = T_STEPS - 1; idx >= 0; --idx) {
        acc |= ((unsigned long long)(unsigned)(s >> 5)) << (idx & 63);
        if ((idx & 63) == 0) {
            out[(size_t)b * T_STEPS + idx + lane] = (float)((acc >> lane) & 1ull);
            acc = 0ull;
        }
        if (idx > 0) {
            const unsigned long long w = tb[idx];         // uniform LDS read, addr indep of s
            s = 2 * (s & 31) + (int)((w >> s) & 1ull);
        }
    }
}

extern "C" void kernel_launch(void* const* d_in, const int* in_sizes, int n_in,
                              void* d_out, int out_size, void* d_ws, size_t ws_size,
                              hipStream_t stream) {
    const float* in = (const float*)d_in[0];
    float* out = (float*)d_out;
    (void)in_sizes; (void)n_in; (void)out_size; (void)d_ws; (void)ws_size;
    viterbi_kernel<<<dim3(512), dim3(64), 0, stream>>>(in, out);
}

// Round 2
// 165.461 us; speedup vs baseline: 1.2796x; 1.2796x over previous
//
#include <hip/hip_runtime.h>
#include <stdint.h>

#define T_STEPS 2048
#define LARGEF  1.0e9f
typedef unsigned long long u64;

// ---- cross-lane exchange per phase (mask basis {1,2,7,15,16,32}) ----
#define XDPP(x, CTRL) __int_as_float(__builtin_amdgcn_update_dpp(0, __float_as_int(x), (CTRL), 0xF, 0xF, true))
#define EXCH0(x) XDPP((x), 0xB1)   // quad_perm [1,0,3,2] : xor 1
#define EXCH1(x) XDPP((x), 0x4E)   // quad_perm [2,3,0,1] : xor 2
#define EXCH2(x) XDPP((x), 0x141)  // row_half_mirror     : xor 7
#define EXCH3(x) XDPP((x), 0x140)  // row_mirror          : xor 15
#define EXCH4(x) __int_as_float(__builtin_amdgcn_ds_swizzle(__float_as_int(x), 0x401F)) // xor 16
#define EXCH5(x) __shfl_xor((x), 32, 64)                                                // xor 32

#define PAR(x) (__builtin_popcount((unsigned)(x)) & 1)

// Per-phase lane constants. D0..D4 = C[(PHI+1+j)%6] for j=0..4, D5 = C[PHI].
// t (branch-metric target) = L_{ts+1}(lane); pd = own predecessor LSB.
#define SETUP(PHI, D0, D1, D2, D3, D4, D5)                                              \
  const int pd##PHI = PAR(lane & (D5));                                                 \
  const int t##PHI = (PAR(lane & (D0))) | (PAR(lane & (D1)) << 1) |                     \
                     (PAR(lane & (D2)) << 2) | (PAR(lane & (D3)) << 3) |                \
                     (PAR(lane & (D4)) << 4) | (pd##PHI << 5);                          \
  const float sa##PHI = 1.0f - 2.0f * (float)PAR(t##PHI & 45);                          \
  const float sb##PHI = 1.0f - 2.0f * (float)PAR(t##PHI & 60);                          \
  const float sae##PHI = pd##PHI ? -sa##PHI : sa##PHI;                                  \
  const float sbe##PHI = pd##PHI ? -sb##PHI : sb##PHI;                                  \
  const u64 pm##PHI = __ballot(pd##PHI);

// One ACS step. candA = own-pred candidate, candB = partner-pred candidate.
// Ballot bit (lane-indexed) = LSB of chosen predecessor, tie -> even pred.
#define FSTEP(PHI, Y0, Y1, WOUT) {                                                      \
    const float bm = fmaf(sae##PHI, (Y0), sbe##PHI * (Y1));                             \
    const float cA = cum + bm;                                                          \
    const float cx = EXCH##PHI(cum);                                                    \
    const float cB = cx - bm;                                                           \
    const u64 bA = __ballot(cB < cA);                                                   \
    const u64 bB = __ballot(cA < cB);                                                   \
    cum = fminf(cA, cB);                                                                \
    (WOUT) = (bB & pm##PHI) | (bA & ~pm##PHI);                                          \
  }

// Traceback step (wave-uniform): bit = c_phi(lam); lam ^= (c^j)?m:0.
#define TSTEP(PHI, IDX, W, CPHI, MPHI) {                                                \
    const int jj = (int)((W) >> lam) & 1;                                               \
    const int cc = PAR(lam & (CPHI));                                                   \
    acc |= ((u64)cc) << ((IDX) & 63);                                                   \
    lam ^= ((cc ^ jj) ? (MPHI) : 0);                                                    \
    if (((IDX) & 63) == 0) {                                                            \
      out[ob + (IDX) + lane] = (float)((acc >> lane) & 1ull);                           \
      acc = 0;                                                                          \
    }                                                                                   \
  }

__global__ __launch_bounds__(64) void viterbi_kernel(const float* __restrict__ in,
                                                     float* __restrict__ out) {
  __shared__ float y_lds[2 * T_STEPS];      // 16 KB staged input row
  __shared__ u64 tb[T_STEPS];               // 16 KB traceback ballots (lane-indexed)

  const int b = blockIdx.x;
  const int lane = threadIdx.x;
  const float* yrow = in + (size_t)b * (2 * T_STEPS);

  // ---- stage y (coalesced float4) ----
  const float4* y4g = (const float4*)yrow;
  float4* y4l = (float4*)y_lds;
#pragma unroll
  for (int i = 0; i < (2 * T_STEPS) / 4 / 64; ++i) y4l[i * 64 + lane] = y4g[i * 64 + lane];
  __syncthreads();

  // ---- per-phase constants: C = {5,6,12,8,16,32}, m = {1,2,7,15,16,32} ----
  SETUP(0, 6, 12, 8, 16, 32, 5)
  SETUP(1, 12, 8, 16, 32, 5, 6)
  SETUP(2, 8, 16, 32, 5, 6, 12)
  SETUP(3, 16, 32, 5, 6, 12, 8)
  SETUP(4, 32, 5, 6, 12, 8, 16)
  SETUP(5, 5, 6, 12, 8, 16, 32)

  // L_0(0) = 0 for any linear labeling: lane 0 holds state 0.
  float cum = (lane == 0) ? 0.0f : LARGEF;

  // ---- forward ACS: 341 macro-steps of 6 phases + 2 remainder ----
  for (int it = 0; it < 341; ++it) {
    const int ts0 = it * 6;
    const float4 ya = y4l[3 * it];
    const float4 yb = y4l[3 * it + 1];
    const float4 yc = y4l[3 * it + 2];
    u64 W0, W1, W2, W3, W4, W5;
    FSTEP(0, ya.x, ya.y, W0)
    FSTEP(1, ya.z, ya.w, W1)
    FSTEP(2, yb.x, yb.y, W2)
    FSTEP(3, yb.z, yb.w, W3)
    FSTEP(4, yc.x, yc.y, W4)
    FSTEP(5, yc.z, yc.w, W5)
    if (lane == 0) {
      tb[ts0 + 0] = W0; tb[ts0 + 1] = W1; tb[ts0 + 2] = W2;
      tb[ts0 + 3] = W3; tb[ts0 + 4] = W4; tb[ts0 + 5] = W5;
    }
  }
  {
    const float4 yz = y4l[1023];
    u64 W0, W1;
    FSTEP(0, yz.x, yz.y, W0)
    FSTEP(1, yz.z, yz.w, W1)
    if (lane == 0) { tb[2046] = W0; tb[2047] = W1; }
  }
  __syncthreads();

  // ---- terminal argmin over STATES (tie -> smallest state number) ----
  // Final labeling = phase (2048 % 6) = 2: bit j from C[(2+j)%6] = {12,8,16,32,5,6}.
  const int stf = PAR(lane & 12) | (PAR(lane & 8) << 1) | (PAR(lane & 16) << 2) |
                  (PAR(lane & 32) << 3) | (PAR(lane & 5) << 4) | (PAR(lane & 6) << 5);
  float v = cum; int bs = stf; int bl = lane;
#pragma unroll
  for (int off = 32; off >= 1; off >>= 1) {
    const float ov = __shfl_xor(v, off, 64);
    const int os = __shfl_xor(bs, off, 64);
    const int ol = __shfl_xor(bl, off, 64);
    if (ov < v || (ov == v && os < bs)) { v = ov; bs = os; bl = ol; }
  }
  int lam = bl;                       // lane-space state, uniform across wave

  // ---- traceback (wave-uniform SALU chain) ----
  const size_t ob = (size_t)b * T_STEPS;
  u64 acc = 0;
  { const u64 W = tb[2047]; TSTEP(1, 2047, W, 6, 2) }
  { const u64 W = tb[2046]; TSTEP(0, 2046, W, 5, 1) }
  for (int it = 340; it >= 0; --it) {
    const int base = it * 6;
    const u64 Wa = tb[base + 5], Wb = tb[base + 4], Wc = tb[base + 3];
    const u64 Wd = tb[base + 2], We = tb[base + 1], Wf = tb[base + 0];
    TSTEP(5, base + 5, Wa, 32, 32)
    TSTEP(4, base + 4, Wb, 16, 16)
    TSTEP(3, base + 3, Wc, 8, 15)
    TSTEP(2, base + 2, Wd, 12, 7)
    TSTEP(1, base + 1, We, 6, 2)
    TSTEP(0, base + 0, Wf, 5, 1)
  }
}

extern "C" void kernel_launch(void* const* d_in, const int* in_sizes, int n_in,
                              void* d_out, int out_size, void* d_ws, size_t ws_size,
                              hipStream_t stream) {
  const float* in = (const float*)d_in[0];
  float* out = (float*)d_out;
  (void)in_sizes; (void)n_in; (void)out_size; (void)d_ws; (void)ws_size;
  viterbi_kernel<<<dim3(512), dim3(64), 0, stream>>>(in, out);
}

// Round 3
// 124.921 us; speedup vs baseline: 1.6949x; 1.3245x over previous
//
#include <hip/hip_runtime.h>
#include <stdint.h>

#define T_STEPS 2048
#define LARGEF  1.0e9f
typedef unsigned long long u64;
typedef unsigned uint2v __attribute__((ext_vector_type(2)));

__device__ __forceinline__ int par6(int x) { return __builtin_popcount((unsigned)x) & 1; }

// phase tables: functionals C, masks m (same algebra as round 2, verified on HW)
constexpr int CARR[6] = {5, 6, 12, 8, 16, 32};
constexpr int MARR[6] = {1, 2, 7, 15, 16, 32};

constexpr u64 ptab_gen(int C) {
  u64 r = 0;
  for (int s = 0; s < 64; ++s) r |= (u64)(__builtin_popcount((unsigned)(s & C)) & 1) << s;
  return r;
}
constexpr u64 PTAB[6] = {ptab_gen(5), ptab_gen(6), ptab_gen(12),
                         ptab_gen(8), ptab_gen(16), ptab_gen(32)};

template<int CTRL>
__device__ __forceinline__ float xdpp(float x) {
  return __int_as_float(__builtin_amdgcn_update_dpp(0, __float_as_int(x), CTRL, 0xF, 0xF, true));
}

__device__ __forceinline__ float exch16(float x, bool use_rx) {
#if __has_builtin(__builtin_amdgcn_permlane16_swap)
  uint2v r = __builtin_amdgcn_permlane16_swap(__float_as_uint(x), __float_as_uint(x), false, false);
  return __uint_as_float(use_rx ? r.x : r.y);
#else
  (void)use_rx;
  return __int_as_float(__builtin_amdgcn_ds_swizzle(__float_as_int(x), 0x401F));
#endif
}
__device__ __forceinline__ float exch32(float x, bool use_rx) {
#if __has_builtin(__builtin_amdgcn_permlane32_swap)
  uint2v r = __builtin_amdgcn_permlane32_swap(__float_as_uint(x), __float_as_uint(x), false, false);
  return __uint_as_float(use_rx ? r.x : r.y);
#else
  (void)use_rx;
  return __shfl_xor(x, 32, 64);
#endif
}

struct Ctx {
  float sae[6], sbe[6];
  bool pd[6];
  bool use_rx16, use_rx32;
};

// ---- forward: 32 steps, start phase SP, bit k of acc = survivor LSB of this lane's state ----
template<int SP, int K>
__device__ __forceinline__ void fwd_steps(float& cum, unsigned& acc, const float* yb, const Ctx& cx) {
  if constexpr (K < 32) {
    constexpr int ph = (SP + K) % 6;
    const float y0 = yb[2 * K];
    const float y1 = yb[2 * K + 1];
    const float bm = fmaf(cx.sae[ph], y0, cx.sbe[ph] * y1);   // bit-exact vs ref
    float ex;
    if constexpr (ph == 0) ex = xdpp<0xB1>(cum);        // xor 1 (quad_perm)
    else if constexpr (ph == 1) ex = xdpp<0x4E>(cum);   // xor 2 (quad_perm)
    else if constexpr (ph == 2) ex = xdpp<0x141>(cum);  // xor 7 (row_half_mirror)
    else if constexpr (ph == 3) ex = xdpp<0x140>(cum);  // xor 15 (row_mirror)
    else if constexpr (ph == 4) ex = exch16(cum, cx.use_rx16);  // xor 16 (permlane16_swap)
    else ex = exch32(cum, cx.use_rx32);                         // xor 32 (permlane32_swap)
    const float cA = cum + bm;          // own-pred candidate
    const float cB = ex - bm;           // partner-pred candidate
    const float ce = cx.pd[ph] ? cB : cA;   // even-pred candidate (tie winner)
    const float co = cx.pd[ph] ? cA : cB;   // odd-pred candidate
    acc |= ((co < ce) ? 1u : 0u) << K;      // survivor LSB; tie -> even (0)
    cum = fminf(cA, cB);
    fwd_steps<SP, K + 1>(cum, acc, yb, cx);
  }
}

// ---- traceback: 32 steps descending; lam is wave-uniform lane-space state ----
template<int SP, int K>
__device__ __forceinline__ void tb_steps(int& lam, unsigned rsrc, unsigned& obits) {
  if constexpr (K >= 0) {
    constexpr int ph = (SP + K) % 6;
    const int j = (__builtin_amdgcn_readlane((int)rsrc, lam) >> K) & 1;
    const int cc = (int)((PTAB[ph] >> lam) & 1);   // decoded bit = c_ph(lam)
    obits |= ((unsigned)cc) << K;
    lam ^= (cc ^ j) ? MARR[ph] : 0;
    tb_steps<SP, K - 1>(lam, rsrc, obits);
  }
}

__global__ __launch_bounds__(64) void viterbi_kernel(const float* __restrict__ in,
                                                     float* __restrict__ out) {
  __shared__ float y_lds[2 * T_STEPS];   // 16 KB staged input row
  __shared__ unsigned tbp[T_STEPS * 2];  // 16 KB: [chunk 32][lane 64][lo,hi]

  const int b = blockIdx.x;
  const int lane = threadIdx.x;
  const float* yrow = in + (size_t)b * (2 * T_STEPS);

  // ---- stage y into LDS (coalesced float4) ----
  const float4* y4g = (const float4*)yrow;
  float4* y4l = (float4*)y_lds;
#pragma unroll
  for (int i = 0; i < (2 * T_STEPS) / 4 / 64; ++i) y4l[i * 64 + lane] = y4g[i * 64 + lane];
  __syncthreads();

  // ---- per-phase lane constants ----
  Ctx cx;
#pragma unroll
  for (int ph = 0; ph < 6; ++ph) {
    const int pdv = par6(lane & CARR[ph]);
    int t = 0;
#pragma unroll
    for (int j = 0; j < 5; ++j) t |= par6(lane & CARR[(ph + 1 + j) % 6]) << j;
    t |= pdv << 5;
    const float sa = 1.0f - 2.0f * (float)par6(t & 45);   // poly 1011011
    const float sb = 1.0f - 2.0f * (float)par6(t & 60);   // poly 1111001
    cx.sae[ph] = pdv ? -sa : sa;
    cx.sbe[ph] = pdv ? -sb : sb;
    cx.pd[ph] = (pdv != 0);
  }
  // ---- probe permlane swap output-register convention (runs once) ----
  {
    const bool oddrow = ((lane >> 4) & 1) != 0;
    const bool lanehi = lane >= 32;
#if __has_builtin(__builtin_amdgcn_permlane16_swap)
    uint2v p16 = __builtin_amdgcn_permlane16_swap((unsigned)lane, (unsigned)lane, false, false);
    const bool rxo = ((unsigned)__builtin_amdgcn_readlane((int)p16.x, 0) == 16u);
    cx.use_rx16 = oddrow ^ rxo;
#else
    cx.use_rx16 = false;
#endif
#if __has_builtin(__builtin_amdgcn_permlane32_swap)
    uint2v p32 = __builtin_amdgcn_permlane32_swap((unsigned)lane, (unsigned)lane, false, false);
    const bool rxh = ((unsigned)__builtin_amdgcn_readlane((int)p32.x, 0) == 32u);
    cx.use_rx32 = lanehi ^ rxh;
#else
    cx.use_rx32 = false;
#endif
  }

  // ---- forward ACS: 64 half-chunks of 32 steps; start phase (2h)%6 in {0,2,4} ----
  float cum = (lane == 0) ? 0.0f : LARGEF;
  unsigned lo_saved = 0;
  int m3 = 0;
  for (int h = 0; h < 64; ++h) {
    unsigned a = 0;
    const float* yb = y_lds + 64 * h;
    if (m3 == 0)      fwd_steps<0, 0>(cum, a, yb, cx);
    else if (m3 == 1) fwd_steps<2, 0>(cum, a, yb, cx);
    else              fwd_steps<4, 0>(cum, a, yb, cx);
    m3 = (m3 == 2) ? 0 : m3 + 1;
    if (h & 1) {
      const int c = h >> 1;
      tbp[(c * 64 + lane) * 2]     = lo_saved;
      tbp[(c * 64 + lane) * 2 + 1] = a;
    } else {
      lo_saved = a;
    }
  }
  __syncthreads();

  // ---- terminal argmin over true states (tie -> smallest state) ----
  // final labeling = phase 2048%6 = 2: bit j from C[(2+j)%6] = {12,8,16,32,5,6}
  const int stf = par6(lane & 12) | (par6(lane & 8) << 1) | (par6(lane & 16) << 2) |
                  (par6(lane & 32) << 3) | (par6(lane & 5) << 4) | (par6(lane & 6) << 5);
  float v = cum; int bs = stf; int bl = lane;
#pragma unroll
  for (int off = 32; off >= 1; off >>= 1) {
    const float ov = __shfl_xor(v, off, 64);
    const int os = __shfl_xor(bs, off, 64);
    const int ol = __shfl_xor(bl, off, 64);
    if (ov < v || (ov == v && os < bs)) { v = ov; bs = os; bl = ol; }
  }
  int lam = __builtin_amdgcn_readfirstlane(bl);

  // ---- traceback: chunks 31..0, halves hi then lo; scalar readlane chain ----
  const size_t ob = (size_t)b * T_STEPS;
  unsigned rlo = tbp[(31 * 64 + lane) * 2];
  unsigned rhi = tbp[(31 * 64 + lane) * 2 + 1];
  int cm3 = 1;  // 31 % 3
  for (int c = 31; c >= 0; --c) {
    unsigned nlo = 0, nhi = 0;
    if (c > 0) {  // prefetch next chunk (addresses independent of lam)
      nlo = tbp[((c - 1) * 64 + lane) * 2];
      nhi = tbp[((c - 1) * 64 + lane) * 2 + 1];
    }
    unsigned obl = 0, obh = 0;
    if (cm3 == 0)      { tb_steps<2, 31>(lam, rhi, obh); tb_steps<0, 31>(lam, rlo, obl); }
    else if (cm3 == 1) { tb_steps<0, 31>(lam, rhi, obh); tb_steps<4, 31>(lam, rlo, obl); }
    else               { tb_steps<4, 31>(lam, rhi, obh); tb_steps<2, 31>(lam, rlo, obl); }
    cm3 = (cm3 == 0) ? 2 : cm3 - 1;
    const unsigned word = (lane >= 32) ? obh : obl;
    out[ob + c * 64 + lane] = (float)((word >> (lane & 31)) & 1u);
    rlo = nlo; rhi = nhi;
  }
}

extern "C" void kernel_launch(void* const* d_in, const int* in_sizes, int n_in,
                              void* d_out, int out_size, void* d_ws, size_t ws_size,
                              hipStream_t stream) {
  const float* in = (const float*)d_in[0];
  float* out = (float*)d_out;
  (void)in_sizes; (void)n_in; (void)out_size; (void)d_ws; (void)ws_size;
  viterbi_kernel<<<dim3(512), dim3(64), 0, stream>>>(in, out);
}